// Round 2
// baseline (353.809 us; speedup 1.0000x reference)
//
#include <hip/hip_runtime.h>
#include <hip/hip_fp16.h>
#include <math.h>

#define SCALE 0.125f   // 64^-0.5

typedef _Float16 f16;
typedef __attribute__((ext_vector_type(8))) _Float16 f16x8;
typedef __attribute__((ext_vector_type(4))) float f32x4;

#define MFMA(a, b, c) __builtin_amdgcn_mfma_f32_16x16x32_f16((a), (b), (c), 0, 0, 0)

// 64-f16 rows (128B = 8 granules of 16B), XOR swizzle: granule g of row r
// lives at slot g ^ (r&7)  -> fragment reads are 2-way (free) banked.
#define LX(r, qd) (((r) << 6) + ((((qd) ^ ((r) & 7))) << 3))

// async global->LDS, 16B/lane; LDS dest = wave-uniform base + lane*16
__device__ __forceinline__ void gll16(const f16* g, f16* l) {
    __builtin_amdgcn_global_load_lds(
        (const __attribute__((address_space(1))) unsigned int*)(g),
        (__attribute__((address_space(3))) unsigned int*)(l),
        16, 0, 0);
}

// manual 16B global load -> VGPR quad; vmcnt-tracked by OUR asm waits only.
__device__ __forceinline__ f16x8 gload16(const f16* p) {
    f16x8 r;
    asm volatile("global_load_dwordx4 %0, %1, off" : "=v"(r) : "v"(p) : "memory");
    return r;
}

// =====================================================================
// split_all: 7 fp32->fp16x2 split segments in one launch (blockIdx.y).
// =====================================================================
struct SplitSeg { const float* src; f16* h; f16* l; float scale; size_t n; };
struct SplitArgs { SplitSeg seg[7]; };

__global__ __launch_bounds__(256) void split_all(SplitArgs a)
{
    SplitSeg s = a.seg[blockIdx.y];
    size_t i4 = ((size_t)blockIdx.x * 256 + threadIdx.x) * 4;
    size_t stride = (size_t)gridDim.x * 256 * 4;
    for (; i4 < s.n; i4 += stride) {
        float4 v = *(const float4*)&s.src[i4];
        float av[4] = {v.x * s.scale, v.y * s.scale, v.z * s.scale, v.w * s.scale};
        f16 hv[4], lv[4];
#pragma unroll
        for (int j = 0; j < 4; ++j) {
            hv[j] = (f16)av[j];
            lv[j] = (f16)(av[j] - (float)hv[j]);
        }
        *(float2*)&s.h[i4] = *(float2*)hv;
        *(float2*)&s.l[i4] = *(float2*)lv;
    }
}

// =====================================================================
// gemm16<AP,BP>: C[M,N] = A @ B^T, fp16-plane decomposition,
// products = AP+BP-1. fp32 accumulate. Tile 128x64, BK=64 (half the
// barrier drains of BK=32), 256 thr = 4 waves (2x2 of 64x32).
// Staging via global_load_lds 16B/lane, swizzle in SOURCE address.
// Epilogue modes (wave-uniform): Cf fp32+bias | Ch(+Cl) row planes |
// Cth(+Ctl) transposed planes | n0>=Nsplit -> C2th single trans plane.
// blockIdx.z batching via Abat/Bbat/Cbat element offsets.
// =====================================================================
template <int AP, int BP>
__global__ __launch_bounds__(256) void gemm16(
    const f16* __restrict__ Ah, const f16* __restrict__ Al, size_t Abat,
    const f16* __restrict__ Bh, const f16* __restrict__ Bl, int Bstr, size_t Bbat,
    float* __restrict__ Cf, const float* __restrict__ bias,
    f16* __restrict__ Ch, f16* __restrict__ Cl, int Cpitch,
    f16* __restrict__ Cth, f16* __restrict__ Ctl, int Mt,
    int Nsplit, f16* __restrict__ C2th, int Mt2,
    size_t Cbat, float oscale, int M, int N, int K)
{
    constexpr int NCH = AP * 16 + BP * 8;      // 1KB staging chunks per k-step
    __shared__ __align__(16) f16 Ash[AP][128 * 64];
    __shared__ __align__(16) f16 Bsh[BP][64 * 64];

    const int tid  = threadIdx.x;
    const int z    = blockIdx.z;
    Ah += z * Abat; if (AP == 2) Al += z * Abat;
    Bh += z * Bbat; if (BP == 2) Bl += z * Bbat;
    const int m0   = blockIdx.y * 128;
    const int n0   = blockIdx.x * 64;
    const int w    = tid >> 6;
    const int lane = tid & 63;
    const int wm   = (w >> 1) * 64;
    const int wn   = (w & 1) * 32;
    const int lq   = lane >> 4;
    const int l15  = lane & 15;
    const int sr   = lane >> 3;                // row-in-chunk 0..7
    const int sg   = lane & 7;                 // physical granule slot

    f32x4 acc[4][2];
#pragma unroll
    for (int mi = 0; mi < 4; ++mi)
#pragma unroll
        for (int ni = 0; ni < 2; ++ni) acc[mi][ni] = (f32x4){0.f, 0.f, 0.f, 0.f};

    for (int k0 = 0; k0 < K; k0 += 64) {
        __syncthreads();
#pragma unroll
        for (int c = 0; c < NCH / 4; ++c) {
            int chunk = c * 4 + w;
            const f16* gp; f16* lp;
            if (chunk < AP * 16) {
                int pl = chunk >> 4, sub = chunk & 15;
                int r = sub * 8 + sr;
                int g = sg ^ (r & 7);
                gp = ((AP == 2 && pl) ? Al : Ah) + (size_t)(m0 + r) * K + k0 + g * 8;
                lp = &Ash[pl][sub * 512];
            } else {
                int cb = chunk - AP * 16;
                int pl = cb >> 3, sub = cb & 7;
                int r = sub * 8 + sr;
                int g = sg ^ (r & 7);
                gp = ((BP == 2 && pl) ? Bl : Bh) + (size_t)(n0 + r) * Bstr + k0 + g * 8;
                lp = &Bsh[pl][sub * 512];
            }
            gll16(gp, lp);
        }
        __syncthreads();

#pragma unroll
        for (int kc = 0; kc < 2; ++kc) {
            f16x8 afh[4], afl[4];
#pragma unroll
            for (int mi = 0; mi < 4; ++mi) {
                int r = wm + mi * 16 + l15;
                afh[mi] = *(const f16x8*)&Ash[0][LX(r, kc * 4 + lq)];
                if (AP == 2) afl[mi] = *(const f16x8*)&Ash[1][LX(r, kc * 4 + lq)];
            }
#pragma unroll
            for (int ni = 0; ni < 2; ++ni) {
                int r = wn + ni * 16 + l15;
                f16x8 bh = *(const f16x8*)&Bsh[0][LX(r, kc * 4 + lq)];
                f16x8 bl;
                if (BP == 2) bl = *(const f16x8*)&Bsh[1][LX(r, kc * 4 + lq)];
#pragma unroll
                for (int mi = 0; mi < 4; ++mi) {
                    f32x4 a = acc[mi][ni];
                    a = MFMA(afh[mi], bh, a);
                    if (BP == 2) a = MFMA(afh[mi], bl, a);
                    if (AP == 2) a = MFMA(afl[mi], bh, a);
                    acc[mi][ni] = a;
                }
            }
        }
    }

    const bool vhalf = (Nsplit > 0) && (n0 >= Nsplit);
    if (Cf)  Cf  += z * Cbat;
    if (Ch)  { Ch += z * Cbat; if (Cl) Cl += z * Cbat; }

#pragma unroll
    for (int mi = 0; mi < 4; ++mi) {
#pragma unroll
        for (int ni = 0; ni < 2; ++ni) {
            int row = m0 + wm + mi * 16 + lq * 4;
            int col = n0 + wn + ni * 16 + l15;
            float v[4];
#pragma unroll
            for (int r = 0; r < 4; ++r) v[r] = acc[mi][ni][r] * oscale;
            if (Cf) {
                float bb = bias ? bias[col] : 0.f;
#pragma unroll
                for (int r = 0; r < 4; ++r)
                    Cf[(size_t)(row + r) * Cpitch + col] = v[r] + bb;
            } else if (vhalf) {
                union { f16 a[4]; float2 f; } uh;
#pragma unroll
                for (int r = 0; r < 4; ++r) uh.a[r] = (f16)v[r];
                *(float2*)&C2th[(size_t)(col - Nsplit) * Mt2 + row] = uh.f;
            } else {
                if (Ch) {
#pragma unroll
                    for (int r = 0; r < 4; ++r) {
                        f16 hh = (f16)v[r];
                        Ch[(size_t)(row + r) * Cpitch + col] = hh;
                        if (Cl) Cl[(size_t)(row + r) * Cpitch + col] = (f16)(v[r] - (float)hh);
                    }
                }
                if (Cth) {
                    union { f16 a[4]; float2 f; } uh, ul;
#pragma unroll
                    for (int r = 0; r < 4; ++r) {
                        uh.a[r] = (f16)v[r];
                        ul.a[r] = (f16)(v[r] - (float)uh.a[r]);
                    }
                    *(float2*)&Cth[(size_t)col * Mt + row] = uh.f;
                    if (Ctl) *(float2*)&Ctl[(size_t)col * Mt + row] = ul.f;
                }
            }
        }
    }
}

// =====================================================================
// MFMA fused FCA attention, tiered precision.
// R2 restructure for occupancy: QBLK=64 (grid.y=32 -> 1024 blocks =
// 4 blocks/CU, 16 waves/CU), KVBLK=32, each wave owns 16 q rows.
// LDS ~29.7KB: K dbuf 8K + G dbuf 16K + Ps 64x40 5K. V tile goes to
// REGISTERS (4x global_load_dwordx4 per wave per jt, L2-resident) ->
// no Vsh, 2 barriers/jt. All VMEM manually vmcnt-counted:
// queue [KG_cur(3)][V(4)][KG_nxt(3)]; vmcnt(7) -> barrier -> QK;
// vmcnt(3) -> PV. Never 0 in steady state.
// fw: 3 products (threshold-critical). Threshold algebra: fn>0.6 <=>
// |fw_raw| > 4.8*(m+1e-6). exp via exp2(fma(s, SCALE*log2e, pen2)).
// =====================================================================
__global__ __launch_bounds__(256, 4) void attn_mfma(
    const f16* __restrict__ Qh, const f16* __restrict__ Ql,
    const f16* __restrict__ Kh,
    const f16* __restrict__ Gh, const f16* __restrict__ Gl,
    const f16* __restrict__ Vth, f16* __restrict__ AOh)
{
    __shared__ __align__(16) f16 Ksh[2][2048];        // K double buffer (32x64)
    __shared__ __align__(16) f16 Gsh[2][2][2048];     // [buf][plane]
    __shared__ __align__(16) f16 Ps[64 * 40];         // P tile, +8 pad
    __shared__ int eflag[4];

    const int tid = threadIdx.x;
    const int bh = blockIdx.x;            // fast dim -> XCD locality per (b,h)
    const int b = bh >> 4, h = bh & 15;
    const int qr0 = blockIdx.y * 64;
    const int w = tid >> 6, lane = tid & 63;
    const int lq = lane >> 4, l15 = lane & 15;
    const int wq = w * 16;                // 16 q rows per wave

    const size_t qb = ((size_t)(b * 2048 + qr0)) * 1024 + h * 64;
    const size_t kb = ((size_t)(b * 1024)) * 1024 + h * 64;
    const size_t vb = (size_t)(h * 64) * 2048 + b * 1024;

    const int sr = lane >> 3;
    const int ss = lane & 7;

    // Q fragments in registers (one 16-row tile per wave)
    f16x8 aqh[2], aql[2];
#pragma unroll
    for (int kc = 0; kc < 2; ++kc) {
        size_t off = qb + (size_t)(wq + l15) * 1024 + (kc * 4 + lq) * 8;
        aqh[kc] = *(const f16x8*)&Qh[off];
        aql[kc] = *(const f16x8*)&Ql[off];
    }

    // ---------------- pass 1: rowmax of min(|fw|,1), early exit ----------------
    float mx[4] = {};
    for (int jt = 0; jt < 32; ++jt) {
#pragma unroll
        for (int c = 0; c < 2; ++c) {
            int chunk = c * 4 + w;               // 0..7
            int pl = chunk >> 2, sub = chunk & 3;
            int r = sub * 8 + sr;
            int g = ss ^ (r & 7);
            const f16* gp = (pl ? Gl : Gh) + kb + (size_t)(jt * 32 + r) * 1024 + g * 8;
            gll16(gp, &Gsh[0][pl][sub * 512]);
        }
        __syncthreads();

#pragma unroll
        for (int tj = 0; tj < 2; ++tj) {
            f32x4 a0 = {0.f, 0.f, 0.f, 0.f};
#pragma unroll
            for (int kc = 0; kc < 2; ++kc) {
                int lx = LX(tj * 16 + l15, kc * 4 + lq);
                f16x8 bgh = *(const f16x8*)&Gsh[0][0][lx];
                f16x8 bgl = *(const f16x8*)&Gsh[0][1][lx];
                a0 = MFMA(aqh[kc], bgh, a0);
                a0 = MFMA(aqh[kc], bgl, a0);
                a0 = MFMA(aql[kc], bgh, a0);
            }
#pragma unroll
            for (int r = 0; r < 4; ++r)
                mx[r] = fmaxf(mx[r], fminf(fabsf(a0[r] * SCALE), 1.f));
        }
        // reduce partials to row maxima (over the 16 l15 lanes)
        bool done = true;
#pragma unroll
        for (int r = 0; r < 4; ++r) {
            float m = mx[r];
#pragma unroll
            for (int d = 1; d < 16; d <<= 1)
                m = fmaxf(m, __shfl_xor(m, d, 64));
            mx[r] = m;
            done = done && (m >= 1.0f);
        }
        int wd = __all(done ? 1 : 0);
        if (lane == 0) eflag[w] = wd;
        __syncthreads();     // eflag visible; also protects Gsh for next stage
        if (eflag[0] && eflag[1] && eflag[2] && eflag[3]) break;
    }
    // per-row |fw_raw| threshold: |fw_raw| > 4.8*(m+1e-6)
    float T[4];
#pragma unroll
    for (int r = 0; r < 4; ++r)
        T[r] = 4.8f * (mx[r] + 1e-6f);

    // ---------------- pass 2: attention (pipelined) ----------------
    const float SL2E = 0.125f * 1.44269504088896f;
    const float PEN2 = -50.0f * 1.44269504088896f;
    f32x4 aco[4];
#pragma unroll
    for (int dj = 0; dj < 4; ++dj) aco[dj] = (f32x4){0.f, 0.f, 0.f, 0.f};
    float dsum[4] = {};

    // KG staging: 12 1KB chunks (K 4 + G 8), 3 per wave
    auto stageKG = [&](int jtn, int buf) {
#pragma unroll
        for (int c = 0; c < 3; ++c) {
            int chunk = c * 4 + w;               // 0..11
            bool isK = chunk < 4;
            int cb = isK ? chunk : chunk - 4;
            int pl = isK ? 0 : (cb >> 2);
            int sub = isK ? cb : (cb & 3);
            int r = sub * 8 + sr;
            int g = ss ^ (r & 7);
            size_t off = kb + (size_t)(jtn * 32 + r) * 1024 + g * 8;
            const f16* gp = isK ? (Kh + off) : ((pl ? Gl : Gh) + off);
            f16* lp = isK ? &Ksh[buf][sub * 512] : &Gsh[buf][pl][sub * 512];
            gll16(gp, lp);
        }
    };

    stageKG(0, 0);   // prologue: KG tile 0 in flight (3/wave)

    for (int jt = 0; jt < 32; ++jt) {
        const int cur = jt & 1;

        // V fragments -> registers (manual loads, vmcnt-tracked by our asm)
        f16x8 vf[4];
#pragma unroll
        for (int dj = 0; dj < 4; ++dj)
            vf[dj] = gload16(&Vth[vb + (size_t)(dj * 16 + l15) * 2048 + jt * 32 + lq * 8]);

        if (jt < 31) {
            stageKG(jt + 1, cur ^ 1);
            // outstanding: KG_cur(3) + V(4) + KG_nxt(3) = 10; retire KG_cur
            asm volatile("s_waitcnt vmcnt(7)" ::: "memory");
        } else {
            // outstanding: KG_cur(3) + V(4) = 7; retire KG_cur
            asm volatile("s_waitcnt vmcnt(4)" ::: "memory");
        }
        __builtin_amdgcn_sched_barrier(0);
        __builtin_amdgcn_s_barrier();            // KG[cur] visible to all waves
        __builtin_amdgcn_sched_barrier(0);

        // QK/FW + softmax from buf[cur]
#pragma unroll
        for (int tj = 0; tj < 2; ++tj) {
            f32x4 s0 = {0.f, 0.f, 0.f, 0.f}, f0 = {0.f, 0.f, 0.f, 0.f};
            __builtin_amdgcn_s_setprio(1);
#pragma unroll
            for (int kc = 0; kc < 2; ++kc) {
                int lx = LX(tj * 16 + l15, kc * 4 + lq);
                f16x8 bkh = *(const f16x8*)&Ksh[cur][lx];
                f16x8 bgh = *(const f16x8*)&Gsh[cur][0][lx];
                f16x8 bgl = *(const f16x8*)&Gsh[cur][1][lx];
                s0 = MFMA(aqh[kc], bkh, s0);
                f0 = MFMA(aqh[kc], bgh, f0);
                f0 = MFMA(aqh[kc], bgl, f0);
                f0 = MFMA(aql[kc], bgh, f0);
            }
            __builtin_amdgcn_s_setprio(0);
#pragma unroll
            for (int r = 0; r < 4; ++r) {
                float p0 = (fabsf(f0[r]) > T[r]) ? 0.f : PEN2;
                f16 e0 = (f16)exp2f(fmaf(s0[r], SL2E, p0));
                Ps[(wq + lq * 4 + r) * 40 + tj * 16 + l15] = e0;
                dsum[r] += (float)e0;
            }
        }

        // retire V (KG_nxt stays in flight), then PV from registers
        if (jt < 31) asm volatile("s_waitcnt vmcnt(3)" ::: "memory");
        else         asm volatile("s_waitcnt vmcnt(0)" ::: "memory");
        __builtin_amdgcn_sched_barrier(0);

        f16x8 ap = *(const f16x8*)&Ps[(wq + l15) * 40 + lq * 8];
        __builtin_amdgcn_s_setprio(1);
#pragma unroll
        for (int dj = 0; dj < 4; ++dj)
            aco[dj] = MFMA(ap, vf[dj], aco[dj]);
        __builtin_amdgcn_s_setprio(0);

        // protect buf[cur] (next jt's stage target) until all QK reads done
        __builtin_amdgcn_sched_barrier(0);
        __builtin_amdgcn_s_barrier();
        __builtin_amdgcn_sched_barrier(0);
    }

    // denominator (in-wave) + single-plane fp16 output
#pragma unroll
    for (int r = 0; r < 4; ++r) {
        float s = dsum[r];
#pragma unroll
        for (int d = 1; d < 16; d <<= 1)
            s += __shfl_xor(s, d, 64);
        dsum[r] = s;
    }
#pragma unroll
    for (int r = 0; r < 4; ++r) {
        float invd = 1.0f / dsum[r];
        int qq = qr0 + wq + lq * 4 + r;
#pragma unroll
        for (int dj = 0; dj < 4; ++dj) {
            int dd = h * 64 + dj * 16 + l15;
            AOh[(size_t)(b * 2048 + qq) * 1024 + dd] = (f16)(aco[dj][r] * invd);
        }
    }
}

// =====================================================================
// Orchestration
// =====================================================================
extern "C" void kernel_launch(void* const* d_in, const int* in_sizes, int n_in,
                              void* d_out, int out_size, void* d_ws, size_t ws_size,
                              hipStream_t stream)
{
    const float* x   = (const float*)d_in[0];
    const float* ctx = (const float*)d_in[1];
    const float* fam = (const float*)d_in[2];
    const float* Wq  = (const float*)d_in[3];
    const float* Wk  = (const float*)d_in[4];
    const float* Wv  = (const float*)d_in[5];
    const float* Wo  = (const float*)d_in[6];
    const float* bo  = (const float*)d_in[7];
    float* out = (float*)d_out;

    const size_t nX  = (size_t)4096 * 1024;
    const size_t nC  = (size_t)2048 * 768;
    const size_t nWq = (size_t)1024 * 1024;
    const size_t nWk = (size_t)1024 * 768;
    const size_t nF  = (size_t)1024 * 1024;
    const size_t nK  = (size_t)2048 * 1024;

    char* p = (char*)d_ws;
    f16 *xh   = (f16*)p; p += nX * 2;   f16 *xl   = (f16*)p; p += nX * 2;
    f16 *ch   = (f16*)p; p += nC * 2;   f16 *cl   = (f16*)p; p += nC * 2;
    f16 *wqh  = (f16*)p; p += nWq * 2;  f16 *wql  = (f16*)p; p += nWq * 2;
    f16 *wkvh = (f16*)p; p += nWk * 4;  f16 *wkvl = (f16*)p; p += nWk * 4;  // [Wk;Wv]
    f16 *woh  = (f16*)p; p += nWq * 2;  f16 *wol  = (f16*)p; p += nWq * 2;
    f16 *fmh  = (f16*)p; p += nF * 2;   f16 *fml  = (f16*)p; p += nF * 2;
    f16 *qh   = (f16*)p; p += nX * 2;   f16 *ql   = (f16*)p; p += nX * 2;
    f16 *kh   = (f16*)p; p += nK * 2;
    f16 *kth  = (f16*)p; p += nK * 2;   f16 *ktl  = (f16*)p; p += nK * 2;
    f16 *vth  = (f16*)p; p += nK * 2;
    f16 *gh   = (f16*)p; p += nK * 2;   f16 *gl   = (f16*)p; p += nK * 2;
    f16 *aoh  = (f16*)p; p += nX * 2;

    const float WS  = 64.0f;       // weight pre-scale (exact pow2)
    const float IWS = 1.0f / 64.0f;

    SplitArgs sa;
    sa.seg[0] = {x,   xh,          xl,          1.f, nX};
    sa.seg[1] = {ctx, ch,          cl,          1.f, nC};
    sa.seg[2] = {Wq,  wqh,         wql,         WS,  nWq};
    sa.seg[3] = {Wk,  wkvh,        wkvl,        WS,  nWk};
    sa.seg[4] = {Wv,  wkvh + nWk,  wkvl + nWk,  WS,  nWk};
    sa.seg[5] = {Wo,  woh,         wol,         WS,  nWq};
    sa.seg[6] = {fam, fmh,         fml,         1.f, nF};
    split_all<<<dim3(64, 7), 256, 0, stream>>>(sa);

    // q = x @ Wq^T : row-major fp16x2 planes (512 blocks, 2/CU)
    gemm16<2, 2><<<dim3(16, 32, 1), 256, 0, stream>>>(
        xh, xl, 0, wqh, wql, 1024, 0,
        nullptr, nullptr, qh, ql, 1024, nullptr, nullptr, 0,
        0, nullptr, 0, 0, IWS, 4096, 1024, 1024);

    // [k|v] = ctx @ [Wk|Wv]^T in one launch (N=2048, 512 blocks).
    gemm16<2, 2><<<dim3(32, 16, 1), 256, 0, stream>>>(
        ch, cl, 0, wkvh, wkvl, 768, 0,
        nullptr, nullptr, kh, nullptr, 1024, kth, ktl, 2048,
        1024, vth, 2048, 0, IWS, 2048, 2048, 768);

    // G_b = fam @ k_b (B = transposed-k planes, batch via z)
    gemm16<2, 2><<<dim3(16, 8, 2), 256, 0, stream>>>(
        fmh, fml, 0, kth, ktl, 2048, 1024,
        nullptr, nullptr, gh, gl, 1024, nullptr, nullptr, 0,
        0, nullptr, 0, (size_t)1024 * 1024, 1.f, 1024, 1024, 1024);

    // fused FCA attention -> single fp16 ao plane (1024 blocks, 4/CU)
    attn_mfma<<<dim3(32, 32), 256, 0, stream>>>(qh, ql, kh, gh, gl, vth, aoh);

    // out = ao @ Wo^T + bo (single-plane 1-product GEMM)
    gemm16<1, 1><<<dim3(16, 32, 1), 256, 0, stream>>>(
        aoh, nullptr, 0, woh, nullptr, 1024, 0,
        out, bo, nullptr, nullptr, 1024, nullptr, nullptr, 0,
        0, nullptr, 0, 0, IWS, 4096, 1024, 1024);
}

// Round 3
// 276.320 us; speedup vs baseline: 1.2804x; 1.2804x over previous
//
#include <hip/hip_runtime.h>
#include <hip/hip_fp16.h>
#include <math.h>

#define SCALE 0.125f   // 64^-0.5

typedef _Float16 f16;
typedef __attribute__((ext_vector_type(8))) _Float16 f16x8;
typedef __attribute__((ext_vector_type(4))) float f32x4;

#define MFMA(a, b, c) __builtin_amdgcn_mfma_f32_16x16x32_f16((a), (b), (c), 0, 0, 0)

// 64-f16 rows (128B = 8 granules of 16B), XOR swizzle: granule g of row r
// lives at slot g ^ (r&7)  -> fragment reads are 2-way (free) banked.
#define LX(r, qd) (((r) << 6) + ((((qd) ^ ((r) & 7))) << 3))

// async global->LDS, 16B/lane; LDS dest = wave-uniform base + lane*16
__device__ __forceinline__ void gll16(const f16* g, f16* l) {
    __builtin_amdgcn_global_load_lds(
        (const __attribute__((address_space(1))) unsigned int*)(g),
        (__attribute__((address_space(3))) unsigned int*)(l),
        16, 0, 0);
}

// =====================================================================
// split_all: 7 fp32->fp16x2 split segments in one launch (blockIdx.y).
// =====================================================================
struct SplitSeg { const float* src; f16* h; f16* l; float scale; size_t n; };
struct SplitArgs { SplitSeg seg[7]; };

__global__ __launch_bounds__(256) void split_all(SplitArgs a)
{
    SplitSeg s = a.seg[blockIdx.y];
    size_t i4 = ((size_t)blockIdx.x * 256 + threadIdx.x) * 4;
    size_t stride = (size_t)gridDim.x * 256 * 4;
    for (; i4 < s.n; i4 += stride) {
        float4 v = *(const float4*)&s.src[i4];
        float av[4] = {v.x * s.scale, v.y * s.scale, v.z * s.scale, v.w * s.scale};
        f16 hv[4], lv[4];
#pragma unroll
        for (int j = 0; j < 4; ++j) {
            hv[j] = (f16)av[j];
            lv[j] = (f16)(av[j] - (float)hv[j]);
        }
        *(float2*)&s.h[i4] = *(float2*)hv;
        *(float2*)&s.l[i4] = *(float2*)lv;
    }
}

// =====================================================================
// gemm16<AP,BP>: C[M,N] = A @ B^T, fp16-plane decomposition,
// products = AP+BP-1. fp32 accumulate. Tile 128x64, BK=64 (half the
// barrier drains of BK=32), 256 thr = 4 waves (2x2 of 64x32).
// Staging via global_load_lds 16B/lane, swizzle in SOURCE address.
// Epilogue modes (wave-uniform): Cf fp32+bias | Ch(+Cl) row planes |
// Cth(+Ctl) transposed planes | n0>=Nsplit -> C2th single trans plane.
// blockIdx.z batching via Abat/Bbat/Cbat element offsets.
// =====================================================================
template <int AP, int BP>
__global__ __launch_bounds__(256) void gemm16(
    const f16* __restrict__ Ah, const f16* __restrict__ Al, size_t Abat,
    const f16* __restrict__ Bh, const f16* __restrict__ Bl, int Bstr, size_t Bbat,
    float* __restrict__ Cf, const float* __restrict__ bias,
    f16* __restrict__ Ch, f16* __restrict__ Cl, int Cpitch,
    f16* __restrict__ Cth, f16* __restrict__ Ctl, int Mt,
    int Nsplit, f16* __restrict__ C2th, int Mt2,
    size_t Cbat, float oscale, int M, int N, int K)
{
    constexpr int NCH = AP * 16 + BP * 8;      // 1KB staging chunks per k-step
    __shared__ __align__(16) f16 Ash[AP][128 * 64];
    __shared__ __align__(16) f16 Bsh[BP][64 * 64];

    const int tid  = threadIdx.x;
    const int z    = blockIdx.z;
    Ah += z * Abat; if (AP == 2) Al += z * Abat;
    Bh += z * Bbat; if (BP == 2) Bl += z * Bbat;
    const int m0   = blockIdx.y * 128;
    const int n0   = blockIdx.x * 64;
    const int w    = tid >> 6;
    const int lane = tid & 63;
    const int wm   = (w >> 1) * 64;
    const int wn   = (w & 1) * 32;
    const int lq   = lane >> 4;
    const int l15  = lane & 15;
    const int sr   = lane >> 3;                // row-in-chunk 0..7
    const int sg   = lane & 7;                 // physical granule slot

    f32x4 acc[4][2];
#pragma unroll
    for (int mi = 0; mi < 4; ++mi)
#pragma unroll
        for (int ni = 0; ni < 2; ++ni) acc[mi][ni] = (f32x4){0.f, 0.f, 0.f, 0.f};

    for (int k0 = 0; k0 < K; k0 += 64) {
        __syncthreads();
#pragma unroll
        for (int c = 0; c < NCH / 4; ++c) {
            int chunk = c * 4 + w;
            const f16* gp; f16* lp;
            if (chunk < AP * 16) {
                int pl = chunk >> 4, sub = chunk & 15;
                int r = sub * 8 + sr;
                int g = sg ^ (r & 7);
                gp = ((AP == 2 && pl) ? Al : Ah) + (size_t)(m0 + r) * K + k0 + g * 8;
                lp = &Ash[pl][sub * 512];
            } else {
                int cb = chunk - AP * 16;
                int pl = cb >> 3, sub = cb & 7;
                int r = sub * 8 + sr;
                int g = sg ^ (r & 7);
                gp = ((BP == 2 && pl) ? Bl : Bh) + (size_t)(n0 + r) * Bstr + k0 + g * 8;
                lp = &Bsh[pl][sub * 512];
            }
            gll16(gp, lp);
        }
        __syncthreads();

#pragma unroll
        for (int kc = 0; kc < 2; ++kc) {
            f16x8 afh[4], afl[4];
#pragma unroll
            for (int mi = 0; mi < 4; ++mi) {
                int r = wm + mi * 16 + l15;
                afh[mi] = *(const f16x8*)&Ash[0][LX(r, kc * 4 + lq)];
                if (AP == 2) afl[mi] = *(const f16x8*)&Ash[1][LX(r, kc * 4 + lq)];
            }
#pragma unroll
            for (int ni = 0; ni < 2; ++ni) {
                int r = wn + ni * 16 + l15;
                f16x8 bh = *(const f16x8*)&Bsh[0][LX(r, kc * 4 + lq)];
                f16x8 bl;
                if (BP == 2) bl = *(const f16x8*)&Bsh[1][LX(r, kc * 4 + lq)];
#pragma unroll
                for (int mi = 0; mi < 4; ++mi) {
                    f32x4 a = acc[mi][ni];
                    a = MFMA(afh[mi], bh, a);
                    if (BP == 2) a = MFMA(afh[mi], bl, a);
                    if (AP == 2) a = MFMA(afl[mi], bh, a);
                    acc[mi][ni] = a;
                }
            }
        }
    }

    const bool vhalf = (Nsplit > 0) && (n0 >= Nsplit);
    if (Cf)  Cf  += z * Cbat;
    if (Ch)  { Ch += z * Cbat; if (Cl) Cl += z * Cbat; }

#pragma unroll
    for (int mi = 0; mi < 4; ++mi) {
#pragma unroll
        for (int ni = 0; ni < 2; ++ni) {
            int row = m0 + wm + mi * 16 + lq * 4;
            int col = n0 + wn + ni * 16 + l15;
            float v[4];
#pragma unroll
            for (int r = 0; r < 4; ++r) v[r] = acc[mi][ni][r] * oscale;
            if (Cf) {
                float bb = bias ? bias[col] : 0.f;
#pragma unroll
                for (int r = 0; r < 4; ++r)
                    Cf[(size_t)(row + r) * Cpitch + col] = v[r] + bb;
            } else if (vhalf) {
                union { f16 a[4]; float2 f; } uh;
#pragma unroll
                for (int r = 0; r < 4; ++r) uh.a[r] = (f16)v[r];
                *(float2*)&C2th[(size_t)(col - Nsplit) * Mt2 + row] = uh.f;
            } else {
                if (Ch) {
#pragma unroll
                    for (int r = 0; r < 4; ++r) {
                        f16 hh = (f16)v[r];
                        Ch[(size_t)(row + r) * Cpitch + col] = hh;
                        if (Cl) Cl[(size_t)(row + r) * Cpitch + col] = (f16)(v[r] - (float)hh);
                    }
                }
                if (Cth) {
                    union { f16 a[4]; float2 f; } uh, ul;
#pragma unroll
                    for (int r = 0; r < 4; ++r) {
                        uh.a[r] = (f16)v[r];
                        ul.a[r] = (f16)(v[r] - (float)uh.a[r]);
                    }
                    *(float2*)&Cth[(size_t)col * Mt + row] = uh.f;
                    if (Ctl) *(float2*)&Ctl[(size_t)col * Mt + row] = ul.f;
                }
            }
        }
    }
}

// =====================================================================
// MFMA fused FCA attention, tiered precision.
// R3: R1 geometry (QBLK=128, KVBLK=64, K/G LDS dbuf + counted vmcnt,
// V LDS single-buffer, 3 barriers/jt) but 512 threads = 8 waves/block.
// Each wave owns 16 q-rows -> same per-BLOCK phase volume as R1
// (320 MFMA between barriers), but 4 waves/SIMD instead of 2 to hide
// ds_read->MFMA->exp2 latency chains. Grid 512 blocks = 2 blocks/CU,
// 16 waves/CU. Per-wave staging: 3 KG chunks + 1 V chunk.
// vmcnt queue per wave: [KG_cur 3][V 1][KG_nxt 3];
//   top:  wait vmcnt(4) retires KG_cur (last jt: vmcnt(1))
//   mid:  wait vmcnt(3) retires V      (last jt: vmcnt(0))
// fw: 3 products (threshold-critical). Threshold algebra: fn>0.6 <=>
// |fw_raw| > 4.8*(m+1e-6). exp via exp2(fma(s, SCALE*log2e, pen2)).
// =====================================================================
__global__ __launch_bounds__(512) void attn_mfma(
    const f16* __restrict__ Qh, const f16* __restrict__ Ql,
    const f16* __restrict__ Kh,
    const f16* __restrict__ Gh, const f16* __restrict__ Gl,
    const f16* __restrict__ Vth, f16* __restrict__ AOh)
{
    __shared__ __align__(16) f16 Ksh[2][4096];        // K double buffer
    __shared__ __align__(16) f16 Gsh[2][2][4096];     // [buf][plane]
    __shared__ __align__(16) f16 Vsh[4096];           // V single buffer
    __shared__ __align__(16) f16 Ps[128 * 72];
    __shared__ int eflag[8];

    const int tid = threadIdx.x;
    const int bh = blockIdx.x;            // fast dim -> XCD locality per (b,h)
    const int b = bh >> 4, h = bh & 15;
    const int qr0 = blockIdx.y * 128;
    const int w = tid >> 6, lane = tid & 63;
    const int lq = lane >> 4, l15 = lane & 15;
    const int wq = w * 16;                // 16 q rows per wave

    const size_t qb = ((size_t)(b * 2048 + qr0)) * 1024 + h * 64;
    const size_t kb = ((size_t)(b * 1024)) * 1024 + h * 64;
    const size_t vb = (size_t)(h * 64) * 2048 + b * 1024;

    const int sr = lane >> 3;
    const int ss = lane & 7;

    // Q fragments in registers (one 16-row tile per wave)
    f16x8 aqh[2], aql[2];
#pragma unroll
    for (int kc = 0; kc < 2; ++kc) {
        size_t off = qb + (size_t)(wq + l15) * 1024 + (kc * 4 + lq) * 8;
        aqh[kc] = *(const f16x8*)&Qh[off];
        aql[kc] = *(const f16x8*)&Ql[off];
    }

    // ---------------- pass 1: rowmax of min(|fw|,1), early exit ----------------
    float mx[4] = {};
    for (int jt = 0; jt < 16; ++jt) {
        // stage G h+l tile (16 KB = 16 chunks, 2 per wave)
#pragma unroll
        for (int c = 0; c < 2; ++c) {
            int chunk = c * 8 + w;               // 0..15
            int pl = chunk >> 3, sub = chunk & 7;
            int r = sub * 8 + sr;
            int g = ss ^ (r & 7);
            const f16* gp = (pl ? Gl : Gh) + kb + (size_t)(jt * 64 + r) * 1024 + g * 8;
            gll16(gp, &Gsh[0][pl][sub * 512]);
        }
        __syncthreads();

#pragma unroll
        for (int tj = 0; tj < 4; ++tj) {
            f32x4 a0 = {0.f, 0.f, 0.f, 0.f};
#pragma unroll
            for (int kc = 0; kc < 2; ++kc) {
                int lx = LX(tj * 16 + l15, kc * 4 + lq);
                f16x8 bgh = *(const f16x8*)&Gsh[0][0][lx];
                f16x8 bgl = *(const f16x8*)&Gsh[0][1][lx];
                a0 = MFMA(aqh[kc], bgh, a0);
                a0 = MFMA(aqh[kc], bgl, a0);
                a0 = MFMA(aql[kc], bgh, a0);
            }
#pragma unroll
            for (int r = 0; r < 4; ++r)
                mx[r] = fmaxf(mx[r], fminf(fabsf(a0[r] * SCALE), 1.f));
        }
        // reduce partials to row maxima (over the 16 l15 lanes)
        bool done = true;
#pragma unroll
        for (int r = 0; r < 4; ++r) {
            float m = mx[r];
#pragma unroll
            for (int d = 1; d < 16; d <<= 1)
                m = fmaxf(m, __shfl_xor(m, d, 64));
            mx[r] = m;
            done = done && (m >= 1.0f);
        }
        int wd = __all(done ? 1 : 0);
        if (lane == 0) eflag[w] = wd;
        __syncthreads();     // eflag visible; also protects Gsh for next stage
        bool allw = true;
#pragma unroll
        for (int i = 0; i < 8; ++i) allw = allw && (eflag[i] != 0);
        if (allw) break;
    }
    // per-row |fw_raw| threshold: |fw_raw| > 4.8*(m+1e-6)
    float T[4];
#pragma unroll
    for (int r = 0; r < 4; ++r)
        T[r] = 4.8f * (mx[r] + 1e-6f);

    // ---------------- pass 2: attention (pipelined) ----------------
    const float SL2E = 0.125f * 1.44269504088896f;
    const float PEN2 = -50.0f * 1.44269504088896f;
    f32x4 aco[4];
#pragma unroll
    for (int dj = 0; dj < 4; ++dj) aco[dj] = (f32x4){0.f, 0.f, 0.f, 0.f};
    float dsum[4] = {};

    // KG staging: 24 1KB chunks (K 8 + Gh 8 + Gl 8), 3 per wave
    auto stageKG = [&](int jtn, int buf) {
#pragma unroll
        for (int c = 0; c < 3; ++c) {
            int chunk = c * 8 + w;               // 0..23
            int sub = chunk & 7;
            int r = sub * 8 + sr;
            int g = ss ^ (r & 7);
            size_t off = kb + (size_t)(jtn * 64 + r) * 1024 + g * 8;
            const f16* gp; f16* lp;
            if (chunk < 8)       { gp = Kh + off; lp = &Ksh[buf][sub * 512]; }
            else if (chunk < 16) { gp = Gh + off; lp = &Gsh[buf][0][sub * 512]; }
            else                 { gp = Gl + off; lp = &Gsh[buf][1][sub * 512]; }
            gll16(gp, lp);
        }
    };

    stageKG(0, 0);   // prologue: KG tile 0 in flight (3/wave)

    for (int jt = 0; jt < 16; ++jt) {
        const int cur = jt & 1;

        // issue V[jt] stage (1 chunk per wave)
        {
            int sub = w;
            int r = sub * 8 + sr;
            int g = ss ^ (r & 7);
            const f16* gp = Vth + vb + (size_t)r * 2048 + jt * 64 + g * 8;
            gll16(gp, &Vsh[sub * 512]);
        }
        // issue K/G[jt+1] stage into the other buffer (3 per wave)
        if (jt < 15) {
            stageKG(jt + 1, cur ^ 1);
            // outstanding: KG_cur(3) + V(1) + KG_nxt(3) = 7; retire KG_cur
            asm volatile("s_waitcnt vmcnt(4)" ::: "memory");
        } else {
            // outstanding: KG_cur(3) + V(1) = 4; retire KG_cur
            asm volatile("s_waitcnt vmcnt(1)" ::: "memory");
        }
        __builtin_amdgcn_sched_barrier(0);
        __builtin_amdgcn_s_barrier();            // KG[cur] visible to all waves
        __builtin_amdgcn_sched_barrier(0);

        // QK/FW + softmax from buf[cur]
#pragma unroll
        for (int tj = 0; tj < 4; ++tj) {
            f32x4 s0 = {0.f, 0.f, 0.f, 0.f}, f0 = {0.f, 0.f, 0.f, 0.f};
            __builtin_amdgcn_s_setprio(1);
#pragma unroll
            for (int kc = 0; kc < 2; ++kc) {
                int lx = LX(tj * 16 + l15, kc * 4 + lq);
                f16x8 bkh = *(const f16x8*)&Ksh[cur][lx];
                f16x8 bgh = *(const f16x8*)&Gsh[cur][0][lx];
                f16x8 bgl = *(const f16x8*)&Gsh[cur][1][lx];
                s0 = MFMA(aqh[kc], bkh, s0);
                f0 = MFMA(aqh[kc], bgh, f0);
                f0 = MFMA(aqh[kc], bgl, f0);
                f0 = MFMA(aql[kc], bgh, f0);
            }
            __builtin_amdgcn_s_setprio(0);
#pragma unroll
            for (int r = 0; r < 4; ++r) {
                float p0 = (fabsf(f0[r]) > T[r]) ? 0.f : PEN2;
                f16 e0 = (f16)exp2f(fmaf(s0[r], SL2E, p0));
                Ps[(wq + lq * 4 + r) * 72 + tj * 16 + l15] = e0;
                dsum[r] += (float)e0;
            }
        }

        // wait exactly the V load (KG_nxt stays in flight)
        if (jt < 15) asm volatile("s_waitcnt vmcnt(3)" ::: "memory");
        else         asm volatile("s_waitcnt vmcnt(0)" ::: "memory");
        asm volatile("s_waitcnt lgkmcnt(0)" ::: "memory");
        __builtin_amdgcn_sched_barrier(0);
        __builtin_amdgcn_s_barrier();            // V visible to all waves
        __builtin_amdgcn_sched_barrier(0);

        // PV: O[q][d] += P[q][c] * V[c][d]   (Ps rows are own-wave only)
        __builtin_amdgcn_s_setprio(1);
#pragma unroll
        for (int kc = 0; kc < 2; ++kc) {
            f16x8 ap = *(const f16x8*)&Ps[(wq + l15) * 72 + kc * 32 + lq * 8];
#pragma unroll
            for (int dj = 0; dj < 4; ++dj) {
                int lx = LX(dj * 16 + l15, kc * 4 + lq);
                f16x8 bvh = *(const f16x8*)&Vsh[lx];
                aco[dj] = MFMA(ap, bvh, aco[dj]);
            }
        }
        __builtin_amdgcn_s_setprio(0);

        // all V/KG reads retired before next iteration's stage overwrites
        asm volatile("s_waitcnt lgkmcnt(0)" ::: "memory");
        __builtin_amdgcn_sched_barrier(0);
        __builtin_amdgcn_s_barrier();
        __builtin_amdgcn_sched_barrier(0);
    }

    // denominator (in-wave) + single-plane fp16 output
#pragma unroll
    for (int r = 0; r < 4; ++r) {
        float s = dsum[r];
#pragma unroll
        for (int d = 1; d < 16; d <<= 1)
            s += __shfl_xor(s, d, 64);
        dsum[r] = s;
    }
#pragma unroll
    for (int r = 0; r < 4; ++r) {
        float invd = 1.0f / dsum[r];
        int qq = qr0 + wq + lq * 4 + r;
#pragma unroll
        for (int dj = 0; dj < 4; ++dj) {
            int dd = h * 64 + dj * 16 + l15;
            AOh[(size_t)(b * 2048 + qq) * 1024 + dd] = (f16)(aco[dj][r] * invd);
        }
    }
}

// =====================================================================
// Orchestration
// =====================================================================
extern "C" void kernel_launch(void* const* d_in, const int* in_sizes, int n_in,
                              void* d_out, int out_size, void* d_ws, size_t ws_size,
                              hipStream_t stream)
{
    const float* x   = (const float*)d_in[0];
    const float* ctx = (const float*)d_in[1];
    const float* fam = (const float*)d_in[2];
    const float* Wq  = (const float*)d_in[3];
    const float* Wk  = (const float*)d_in[4];
    const float* Wv  = (const float*)d_in[5];
    const float* Wo  = (const float*)d_in[6];
    const float* bo  = (const float*)d_in[7];
    float* out = (float*)d_out;

    const size_t nX  = (size_t)4096 * 1024;
    const size_t nC  = (size_t)2048 * 768;
    const size_t nWq = (size_t)1024 * 1024;
    const size_t nWk = (size_t)1024 * 768;
    const size_t nF  = (size_t)1024 * 1024;
    const size_t nK  = (size_t)2048 * 1024;

    char* p = (char*)d_ws;
    f16 *xh   = (f16*)p; p += nX * 2;   f16 *xl   = (f16*)p; p += nX * 2;
    f16 *ch   = (f16*)p; p += nC * 2;   f16 *cl   = (f16*)p; p += nC * 2;
    f16 *wqh  = (f16*)p; p += nWq * 2;  f16 *wql  = (f16*)p; p += nWq * 2;
    f16 *wkvh = (f16*)p; p += nWk * 4;  f16 *wkvl = (f16*)p; p += nWk * 4;  // [Wk;Wv]
    f16 *woh  = (f16*)p; p += nWq * 2;  f16 *wol  = (f16*)p; p += nWq * 2;
    f16 *fmh  = (f16*)p; p += nF * 2;   f16 *fml  = (f16*)p; p += nF * 2;
    f16 *qh   = (f16*)p; p += nX * 2;   f16 *ql   = (f16*)p; p += nX * 2;
    f16 *kh   = (f16*)p; p += nK * 2;
    f16 *kth  = (f16*)p; p += nK * 2;   f16 *ktl  = (f16*)p; p += nK * 2;
    f16 *vth  = (f16*)p; p += nK * 2;
    f16 *gh   = (f16*)p; p += nK * 2;   f16 *gl   = (f16*)p; p += nK * 2;
    f16 *aoh  = (f16*)p; p += nX * 2;

    const float WS  = 64.0f;       // weight pre-scale (exact pow2)
    const float IWS = 1.0f / 64.0f;

    SplitArgs sa;
    sa.seg[0] = {x,   xh,          xl,          1.f, nX};
    sa.seg[1] = {ctx, ch,          cl,          1.f, nC};
    sa.seg[2] = {Wq,  wqh,         wql,         WS,  nWq};
    sa.seg[3] = {Wk,  wkvh,        wkvl,        WS,  nWk};
    sa.seg[4] = {Wv,  wkvh + nWk,  wkvl + nWk,  WS,  nWk};
    sa.seg[5] = {Wo,  woh,         wol,         WS,  nWq};
    sa.seg[6] = {fam, fmh,         fml,         1.f, nF};
    split_all<<<dim3(64, 7), 256, 0, stream>>>(sa);

    // q = x @ Wq^T : row-major fp16x2 planes (512 blocks, 2/CU)
    gemm16<2, 2><<<dim3(16, 32, 1), 256, 0, stream>>>(
        xh, xl, 0, wqh, wql, 1024, 0,
        nullptr, nullptr, qh, ql, 1024, nullptr, nullptr, 0,
        0, nullptr, 0, 0, IWS, 4096, 1024, 1024);

    // [k|v] = ctx @ [Wk|Wv]^T in one launch (N=2048, 512 blocks).
    gemm16<2, 2><<<dim3(32, 16, 1), 256, 0, stream>>>(
        ch, cl, 0, wkvh, wkvl, 768, 0,
        nullptr, nullptr, kh, nullptr, 1024, kth, ktl, 2048,
        1024, vth, 2048, 0, IWS, 2048, 2048, 768);

    // G_b = fam @ k_b (B = transposed-k planes, batch via z)
    gemm16<2, 2><<<dim3(16, 8, 2), 256, 0, stream>>>(
        fmh, fml, 0, kth, ktl, 2048, 1024,
        nullptr, nullptr, gh, gl, 1024, nullptr, nullptr, 0,
        0, nullptr, 0, (size_t)1024 * 1024, 1.f, 1024, 1024, 1024);

    // fused FCA attention -> single fp16 ao plane (512 blocks x 8 waves)
    attn_mfma<<<dim3(32, 16), 512, 0, stream>>>(qh, ql, kh, gh, gl, vth, aoh);

    // out = ao @ Wo^T + bo (single-plane 1-product GEMM)
    gemm16<1, 1><<<dim3(16, 32, 1), 256, 0, stream>>>(
        aoh, nullptr, 0, woh, nullptr, 1024, 0,
        out, bo, nullptr, nullptr, 1024, nullptr, nullptr, 0,
        0, nullptr, 0, 0, IWS, 4096, 1024, 1024);
}